// Round 3
// baseline (293.388 us; speedup 1.0000x reference)
//
#include <hip/hip_runtime.h>
#include <math.h>

#define TT 1024
#define DD 512
#define KK 64
#define OO 1024
#define EPSF 1e-12f

typedef __attribute__((ext_vector_type(8))) short bf16x8;
typedef __attribute__((ext_vector_type(4))) float f32x4;

__device__ __forceinline__ ushort f2bf(float f) {
  unsigned u = __float_as_uint(f);
  u = (u + 0x7FFFu + ((u >> 16) & 1u)) >> 16;
  return (ushort)u;
}
__device__ __forceinline__ float bf2f(ushort h) {
  return __uint_as_float(((unsigned)h) << 16);
}

// ws layout (float units):
//  xaggP  f32 [8][32][64][512] = 8388608 @ 0
//  full   f32 [32][64*512]     = 1048576 @ 8388608
//  fullT  f32 [32768][32]      = 1048576 @ 9437184
//  outP   f32 [64][32][1024]   = 2097152 @ 10485760
//  whT    bf16[64][512]        = 16384 f @ 14680064
//  sum_w  @ 14696448 ; s1 +2048

// ---------------- K0: whT[k][d] <- weight[d][k]; zero sum_w ----------------
__global__ __launch_bounds__(256) void nv_k0(const float* __restrict__ w,
                                             ushort* __restrict__ whT,
                                             float* __restrict__ sum_w) {
  int idx = blockIdx.x * 256 + threadIdx.x;
  if (idx < 32768) {
    int d = idx >> 6, k = idx & 63;
    whT[(size_t)k * DD + d] = f2bf(w[idx]);
  } else if (idx < 32768 + 2048) {
    sum_w[idx - 32768] = 0.f;
  }
}

// ---------------- K12: fused softmax-assign + aggregate ----------------
// block: (tsp, b), t-tile = 128, 8 waves. Phase A: COALESCED staged loads
// (x -> xs, whT -> wsm per 64-d chunk), MFMA frags from LDS; the same x
// registers are also deposited transposed into the persistent xT tile, so
// x is read from HBM exactly once. Phase B runs entirely out of xT + aTl.
// LDS: xT 128K + union{xs,aTl} 16K + wsm 8K = 152 KB.
__global__ __launch_bounds__(512) void nv_k12(
    const float* __restrict__ x, const ushort* __restrict__ whT,
    const float* __restrict__ bias, float* __restrict__ xaggP,
    float* __restrict__ sum_w) {
  const int tsp = blockIdx.x, b = blockIdx.y;
  const int t0 = tsp * 128;
  const int tid = threadIdx.x;
  const int wave = tid >> 6, lane = tid & 63, l15 = lane & 15, q = lane >> 4;

  __shared__ ushort xT[512 * 128];  // [d][t-granule], slot g^(d&15)   128 KB
  __shared__ ushort xsa[128 * 64];  // phase A: xs[t][dg]; later aTl[k][tg] 16 KB
  __shared__ ushort wsm[64 * 64];   // [k][d-granule], slot g^(k&7)      8 KB
  ushort* xs = xsa;
  ushort* aTl = xsa;

  // ---------- phase A: logits, x read ONCE, all loads coalesced ----------
  f32x4 acc[4];
#pragma unroll
  for (int nt = 0; nt < 4; ++nt)
#pragma unroll
    for (int r = 0; r < 4; ++r) acc[nt][r] = 0.f;

  for (int dc = 0; dc < DD; dc += 64) {
    // stage x chunk (coalesced) + deposit transposed copy into xT
#pragma unroll
    for (int it = 0; it < 2; ++it) {
      int gi = it * 512 + tid;  // 0..1023 granules (128 t x 8 gd)
      int t = gi >> 3, gd = gi & 7;
      const float* px = x + (size_t)(b * TT + t0 + t) * DD + dc + gd * 8;
      float4 v0 = *(const float4*)px;
      float4 v1 = *(const float4*)(px + 4);
      bf16x8 pk;
      pk[0] = (short)f2bf(v0.x); pk[1] = (short)f2bf(v0.y);
      pk[2] = (short)f2bf(v0.z); pk[3] = (short)f2bf(v0.w);
      pk[4] = (short)f2bf(v1.x); pk[5] = (short)f2bf(v1.y);
      pk[6] = (short)f2bf(v1.z); pk[7] = (short)f2bf(v1.w);
      *(bf16x8*)(xs + t * 64 + ((gd ^ (t & 7)) << 3)) = pk;
      const int tg = t >> 3, tlo = t & 7;
#pragma unroll
      for (int j = 0; j < 8; ++j) {
        const int d = dc + gd * 8 + j;
        xT[d * 128 + ((tg ^ (d & 15)) << 3) + tlo] = (ushort)pk[j];
      }
    }
    // stage W chunk (coalesced): 512 threads cover 64 k x 8 granules
    {
      int k = tid >> 3, gd = tid & 7;
      bf16x8 v = *(const bf16x8*)(whT + (size_t)k * DD + dc + gd * 8);
      *(bf16x8*)(wsm + k * 64 + ((gd ^ (k & 7)) << 3)) = v;
    }
    __syncthreads();
#pragma unroll
    for (int kc = 0; kc < 2; ++kc) {
      const int gq = kc * 4 + q;
      bf16x8 bfv[4];
#pragma unroll
      for (int nt = 0; nt < 4; ++nt) {
        const int k = nt * 16 + l15;
        bfv[nt] = *(const bf16x8*)(wsm + k * 64 + ((gq ^ (k & 7)) << 3));
      }
      const int t = wave * 16 + l15;
      bf16x8 af = *(const bf16x8*)(xs + t * 64 + ((gq ^ (t & 7)) << 3));
#pragma unroll
      for (int nt = 0; nt < 4; ++nt)
        acc[nt] = __builtin_amdgcn_mfma_f32_16x16x32_bf16(af, bfv[nt], acc[nt], 0, 0, 0);
    }
    __syncthreads();
  }

  // softmax epilogue: rows t = wave*16 + q*4 + r; cols k = nt*16 + l15
  float bia[4];
#pragma unroll
  for (int nt = 0; nt < 4; ++nt) bia[nt] = bias[nt * 16 + l15];

  ushort au[4][4];
  float sw[4] = {0.f, 0.f, 0.f, 0.f};
#pragma unroll
  for (int r = 0; r < 4; ++r) {
    float l[4];
#pragma unroll
    for (int nt = 0; nt < 4; ++nt) l[nt] = acc[nt][r] + bia[nt];
    float m = fmaxf(fmaxf(l[0], l[1]), fmaxf(l[2], l[3]));
#pragma unroll
    for (int s = 1; s <= 8; s <<= 1) m = fmaxf(m, __shfl_xor(m, s));
    float e[4];
#pragma unroll
    for (int nt = 0; nt < 4; ++nt) e[nt] = __expf(l[nt] - m);
    float ssum = e[0] + e[1] + e[2] + e[3];
#pragma unroll
    for (int s = 1; s <= 8; s <<= 1) ssum += __shfl_xor(ssum, s);
    float inv = 1.f / ssum;
#pragma unroll
    for (int nt = 0; nt < 4; ++nt) {
      ushort u = f2bf(e[nt] * inv);
      au[nt][r] = u;
      sw[nt] += bf2f(u);
    }
  }
#pragma unroll
  for (int nt = 0; nt < 4; ++nt) {
    float s = sw[nt];
    s += __shfl_xor(s, 16);
    s += __shfl_xor(s, 32);
    if (q == 0) atomicAdd(sum_w + b * KK + nt * 16 + l15, s);
  }

  // xs is dead; reuse the buffer as aTl. Barrier first: other waves may
  // still be in their last phase-A MFMA reading xs.
  __syncthreads();
#pragma unroll
  for (int nt = 0; nt < 4; ++nt)
#pragma unroll
    for (int r = 0; r < 4; ++r) {
      const int k = nt * 16 + l15;
      const int t = wave * 16 + q * 4 + r;
      aTl[k * 128 + (((t >> 3) ^ (k & 15)) << 3) + (t & 7)] = au[nt][r];
    }
  __syncthreads();

  // ---------- phase B: xagg[k][d] = aT @ x, all from LDS ----------
  f32x4 accB[4][4];
#pragma unroll
  for (int mk = 0; mk < 4; ++mk)
#pragma unroll
    for (int nd = 0; nd < 4; ++nd)
#pragma unroll
      for (int r = 0; r < 4; ++r) accB[mk][nd][r] = 0.f;

#pragma unroll
  for (int kc = 0; kc < 4; ++kc) {
    const int g = kc * 4 + q;
    bf16x8 afr[4], bfr[4];
#pragma unroll
    for (int mk = 0; mk < 4; ++mk) {
      const int k = mk * 16 + l15;
      afr[mk] = *(const bf16x8*)(aTl + k * 128 + ((g ^ (k & 15)) << 3));
    }
#pragma unroll
    for (int nd = 0; nd < 4; ++nd) {
      const int d = wave * 64 + nd * 16 + l15;
      bfr[nd] = *(const bf16x8*)(xT + d * 128 + ((g ^ (d & 15)) << 3));
    }
#pragma unroll
    for (int mk = 0; mk < 4; ++mk)
#pragma unroll
      for (int nd = 0; nd < 4; ++nd)
        accB[mk][nd] =
            __builtin_amdgcn_mfma_f32_16x16x32_bf16(afr[mk], bfr[nd], accB[mk][nd], 0, 0, 0);
  }
  // write: row k = mk*16 + q*4 + r, col d = wave*64 + nd*16 + l15
#pragma unroll
  for (int mk = 0; mk < 4; ++mk)
#pragma unroll
    for (int nd = 0; nd < 4; ++nd)
#pragma unroll
      for (int r = 0; r < 4; ++r) {
        const int k = mk * 16 + q * 4 + r;
        const int d = wave * 64 + nd * 16 + l15;
        xaggP[(size_t)((tsp * 32 + b) * KK + k) * DD + d] = accB[mk][nd][r];
      }
}

// ---------------- K3a: sum 8 partials, residual, per-(b,k) sumsq ----------------
__global__ __launch_bounds__(128) void nv_k3a(
    const float* __restrict__ xaggP, float* __restrict__ full,
    const float* __restrict__ centers, const float* __restrict__ sum_w,
    float* __restrict__ s1) {
  const int k = blockIdx.x, b = blockIdx.y;
  const int tid = threadIdx.x;
  const float sw = sum_w[b * KK + k];
  float4 v = make_float4(0.f, 0.f, 0.f, 0.f);
#pragma unroll
  for (int sp = 0; sp < 8; ++sp) {
    float4 p = *((const float4*)(xaggP + (size_t)((sp * 32 + b) * KK + k) * DD) + tid);
    v.x += p.x; v.y += p.y; v.z += p.z; v.w += p.w;
  }
  float4 c = *((const float4*)(centers + (size_t)k * DD) + tid);
  v.x = fmaf(-sw, c.x, v.x);
  v.y = fmaf(-sw, c.y, v.y);
  v.z = fmaf(-sw, c.z, v.z);
  v.w = fmaf(-sw, c.w, v.w);
  *((float4*)(full + (size_t)(b * KK + k) * DD) + tid) = v;
  float ss = v.x * v.x + v.y * v.y + v.z * v.z + v.w * v.w;
#pragma unroll
  for (int s = 1; s <= 32; s <<= 1) ss += __shfl_xor(ss, s);
  __shared__ float red[2];
  if ((tid & 63) == 0) red[tid >> 6] = ss;
  __syncthreads();
  if (tid == 0) s1[b * KK + k] = red[0] + red[1];
}

// ---------------- K3c: scale + transpose -> fullT[r][b] (K3b folded in) ----------------
// block (k, dchunk of 128): recompute per-b second-norm sum from s1 (8 KB,
// L2-hot), then stage scaled [32 b][128 d] to LDS, write [128 d][32 b].
__global__ __launch_bounds__(256) void nv_k3c(const float* __restrict__ full,
                                              const float* __restrict__ s1,
                                              float* __restrict__ fullT) {
  const int k = blockIdx.x, d0 = blockIdx.y * 128;
  const int tid = threadIdx.x;
  __shared__ float ls[32 * 132];  // [b][d], pad 132
  __shared__ float s2s[32];

  {
    int bb = tid >> 3, k8 = tid & 7;
    float p = 0.f;
#pragma unroll
    for (int i = 0; i < 8; ++i) {
      float r = s1[bb * KK + k8 * 8 + i];
      p += r / fmaxf(r, EPSF);
    }
    p += __shfl_xor(p, 1);
    p += __shfl_xor(p, 2);
    p += __shfl_xor(p, 4);
    if (k8 == 0) s2s[bb] = rsqrtf(fmaxf(p, EPSF));
  }
  __syncthreads();

#pragma unroll
  for (int it = 0; it < 4; ++it) {
    int fi = it * 256 + tid;  // 1024 float4s
    int b = fi >> 5, dg = fi & 31;
    float r = s1[b * KK + k];
    float sc = rsqrtf(fmaxf(r, EPSF)) * s2s[b];
    float4 v = *((const float4*)(full + (size_t)(b * KK + k) * DD + d0) + dg);
    v.x *= sc; v.y *= sc; v.z *= sc; v.w *= sc;
    *(float4*)(ls + b * 132 + dg * 4) = v;
  }
  __syncthreads();
#pragma unroll
  for (int it = 0; it < 4; ++it) {
    int fo = it * 256 + tid;  // 1024 float4s
    int d = fo >> 3, bq = fo & 7;
    float4 v;
    v.x = ls[(bq * 4 + 0) * 132 + d];
    v.y = ls[(bq * 4 + 1) * 132 + d];
    v.z = ls[(bq * 4 + 2) * 132 + d];
    v.w = ls[(bq * 4 + 3) * 132 + d];
    *(float4*)(fullT + (size_t)(k * DD + d0 + d) * 32 + bq * 4) = v;
  }
}

// ---------------- K4: GEMV-bundle, 512-row k-span, 8-deep load pipeline ----------------
// grid (4 strips, 64 ksp). Each block covers k-rows [ksp*512, ksp*512+512)
// in two 256-row chunks (fst re-staged, acc carried in registers), halving
// the outP partial traffic vs the (4,128) version.
__global__ __launch_bounds__(256) void nv_k4(
    const float* __restrict__ fullT, const float* __restrict__ reduc,
    float* __restrict__ outP) {
  const int strip = blockIdx.x;  // 4
  const int ksp = blockIdx.y;    // 64
  const int tid = threadIdx.x;
  const int wave = tid >> 6, lane = tid & 63;
  const int c0 = strip * 256 + lane * 4;

  __shared__ float fst[256 * 32];  // [k_local][b]; reused as red[32][256]

  float4 acc[32];
#pragma unroll
  for (int b = 0; b < 32; ++b) acc[b] = make_float4(0.f, 0.f, 0.f, 0.f);

  for (int chunk = 0; chunk < 2; ++chunk) {
    const int kblk = ksp * 512 + chunk * 256;
    __syncthreads();  // fst reuse guard (no-op cost on first iter)
#pragma unroll
    for (int it = 0; it < 8; ++it) {
      int f4 = it * 256 + tid;
      *(float4*)(fst + f4 * 4) = *(const float4*)(fullT + (size_t)kblk * 32 + f4 * 4);
    }
    __syncthreads();

    const int kw = wave * 64;
    for (int kk = 0; kk < 64; kk += 8) {
      float4 rv[8];
#pragma unroll
      for (int j = 0; j < 8; ++j)
        rv[j] = *(const float4*)(reduc + (size_t)(kblk + kw + kk + j) * OO + c0);
#pragma unroll
      for (int j = 0; j < 8; ++j) {
        const int kl = kw + kk + j;
#pragma unroll
        for (int b4 = 0; b4 < 8; ++b4) {
          float4 fv = *(const float4*)(fst + kl * 32 + b4 * 4);
          acc[b4 * 4 + 0].x = fmaf(fv.x, rv[j].x, acc[b4 * 4 + 0].x);
          acc[b4 * 4 + 0].y = fmaf(fv.x, rv[j].y, acc[b4 * 4 + 0].y);
          acc[b4 * 4 + 0].z = fmaf(fv.x, rv[j].z, acc[b4 * 4 + 0].z);
          acc[b4 * 4 + 0].w = fmaf(fv.x, rv[j].w, acc[b4 * 4 + 0].w);
          acc[b4 * 4 + 1].x = fmaf(fv.y, rv[j].x, acc[b4 * 4 + 1].x);
          acc[b4 * 4 + 1].y = fmaf(fv.y, rv[j].y, acc[b4 * 4 + 1].y);
          acc[b4 * 4 + 1].z = fmaf(fv.y, rv[j].z, acc[b4 * 4 + 1].z);
          acc[b4 * 4 + 1].w = fmaf(fv.y, rv[j].w, acc[b4 * 4 + 1].w);
          acc[b4 * 4 + 2].x = fmaf(fv.z, rv[j].x, acc[b4 * 4 + 2].x);
          acc[b4 * 4 + 2].y = fmaf(fv.z, rv[j].y, acc[b4 * 4 + 2].y);
          acc[b4 * 4 + 2].z = fmaf(fv.z, rv[j].z, acc[b4 * 4 + 2].z);
          acc[b4 * 4 + 2].w = fmaf(fv.z, rv[j].w, acc[b4 * 4 + 2].w);
          acc[b4 * 4 + 3].x = fmaf(fv.w, rv[j].x, acc[b4 * 4 + 3].x);
          acc[b4 * 4 + 3].y = fmaf(fv.w, rv[j].y, acc[b4 * 4 + 3].y);
          acc[b4 * 4 + 3].z = fmaf(fv.w, rv[j].z, acc[b4 * 4 + 3].z);
          acc[b4 * 4 + 3].w = fmaf(fv.w, rv[j].w, acc[b4 * 4 + 3].w);
        }
      }
    }
  }

  __syncthreads();
  for (int w = 0; w < 4; ++w) {
    if (wave == w) {
      if (w == 0) {
#pragma unroll
        for (int b = 0; b < 32; ++b)
          *(float4*)(fst + b * 256 + lane * 4) = acc[b];
      } else {
#pragma unroll
        for (int b = 0; b < 32; ++b) {
          float4 v = *(float4*)(fst + b * 256 + lane * 4);
          v.x += acc[b].x; v.y += acc[b].y; v.z += acc[b].z; v.w += acc[b].w;
          *(float4*)(fst + b * 256 + lane * 4) = v;
        }
      }
    }
    __syncthreads();
  }

#pragma unroll
  for (int it = 0; it < 8; ++it) {
    int f4 = it * 256 + tid;
    int b = f4 >> 6, cg = f4 & 63;
    *(float4*)(outP + ((size_t)(ksp * 32 + b) * OO) + strip * 256 + cg * 4) =
        *(const float4*)(fst + b * 256 + cg * 4);
  }
}

// ---------------- K5: out = sum over 64 k-splits ----------------
__global__ __launch_bounds__(128) void nv_k5(const float* __restrict__ outP,
                                             float* __restrict__ out) {
  const int idx = blockIdx.x * 128 + threadIdx.x;  // 0..32767
  float s = 0.f;
#pragma unroll 8
  for (int sp = 0; sp < 64; ++sp) s += outP[(size_t)sp * 32768 + idx];
  out[idx] = s;
}

extern "C" void kernel_launch(void* const* d_in, const int* in_sizes, int n_in,
                              void* d_out, int out_size, void* d_ws, size_t ws_size,
                              hipStream_t stream) {
  const float* x = (const float*)d_in[0];
  const float* weight = (const float*)d_in[1];
  const float* bias = (const float*)d_in[2];
  const float* centers = (const float*)d_in[3];
  const float* reduc = (const float*)d_in[4];
  float* out = (float*)d_out;
  float* ws = (float*)d_ws;

  float* xaggP = ws;                          // [0, 8M)
  float* full = ws + 8388608;                 // [8M, 9M)
  float* fullT = ws + 9437184;                // [9M, 10M)
  float* outP = ws + 10485760;                // [10M, 12M)
  ushort* whT = (ushort*)(ws + 14680064);     // 32768 ushorts
  float* sum_w = ws + 14696448;
  float* s1 = sum_w + 2048;

  nv_k0<<<136, 256, 0, stream>>>(weight, whT, sum_w);
  nv_k12<<<dim3(8, 32), 512, 0, stream>>>(x, whT, bias, xaggP, sum_w);
  nv_k3a<<<dim3(64, 32), 128, 0, stream>>>(xaggP, full, centers, sum_w, s1);
  nv_k3c<<<dim3(64, 4), 256, 0, stream>>>(full, s1, fullT);
  nv_k4<<<dim3(4, 64), 256, 0, stream>>>(fullT, reduc, outP);
  nv_k5<<<256, 128, 0, stream>>>(outP, out);
}

// Round 4
// 286.482 us; speedup vs baseline: 1.0241x; 1.0241x over previous
//
#include <hip/hip_runtime.h>
#include <math.h>

#define TT 1024
#define DD 512
#define KK 64
#define OO 1024
#define EPSF 1e-12f

typedef __attribute__((ext_vector_type(8))) short bf16x8;
typedef __attribute__((ext_vector_type(4))) float f32x4;

__device__ __forceinline__ ushort f2bf(float f) {
  unsigned u = __float_as_uint(f);
  u = (u + 0x7FFFu + ((u >> 16) & 1u)) >> 16;
  return (ushort)u;
}
__device__ __forceinline__ float bf2f(ushort h) {
  return __uint_as_float(((unsigned)h) << 16);
}

// ws layout (float units):
//  xaggP  f32 [8][32][64][512] = 8388608 @ 0
//  full   f32 [32][64*512]     = 1048576 @ 8388608
//  fullT  f32 [32768][32]      = 1048576 @ 9437184
//  outP   f32 [256][32][1024]  = 8388608 @ 10485760
//  whT    bf16[64][512]        = 16384 f @ 18874368
//  sum_w  @ 18890752 ; s1 +2048

// ---------------- K0: whT[k][d] <- weight[d][k]; zero sum_w ----------------
__global__ __launch_bounds__(256) void nv_k0(const float* __restrict__ w,
                                             ushort* __restrict__ whT,
                                             float* __restrict__ sum_w) {
  int idx = blockIdx.x * 256 + threadIdx.x;
  if (idx < 32768) {
    int d = idx >> 6, k = idx & 63;
    whT[(size_t)k * DD + d] = f2bf(w[idx]);
  } else if (idx < 32768 + 2048) {
    sum_w[idx - 32768] = 0.f;
  }
}

// ---------------- K12: fused softmax-assign + aggregate ----------------
// block: (tsp, b), t-tile = 128, 8 waves. Phase A: COALESCED staged loads
// (x -> xs, whT -> wsm per 64-d chunk), MFMA frags from LDS; the same x
// registers are also deposited transposed into the persistent xT tile, so
// x is read from HBM exactly once. Phase B runs entirely out of xT + aTl.
// LDS: xT 128K + union{xs,aTl} 16K + wsm 8K = 152 KB.
__global__ __launch_bounds__(512) void nv_k12(
    const float* __restrict__ x, const ushort* __restrict__ whT,
    const float* __restrict__ bias, float* __restrict__ xaggP,
    float* __restrict__ sum_w) {
  const int tsp = blockIdx.x, b = blockIdx.y;
  const int t0 = tsp * 128;
  const int tid = threadIdx.x;
  const int wave = tid >> 6, lane = tid & 63, l15 = lane & 15, q = lane >> 4;

  __shared__ ushort xT[512 * 128];  // [d][t-granule], slot g^(d&15)   128 KB
  __shared__ ushort xsa[128 * 64];  // phase A: xs[t][dg]; later aTl[k][tg] 16 KB
  __shared__ ushort wsm[64 * 64];   // [k][d-granule], slot g^(k&7)      8 KB
  ushort* xs = xsa;
  ushort* aTl = xsa;

  // ---------- phase A: logits, x read ONCE, all loads coalesced ----------
  f32x4 acc[4];
#pragma unroll
  for (int nt = 0; nt < 4; ++nt)
#pragma unroll
    for (int r = 0; r < 4; ++r) acc[nt][r] = 0.f;

  for (int dc = 0; dc < DD; dc += 64) {
    // stage x chunk (coalesced) + deposit transposed copy into xT
#pragma unroll
    for (int it = 0; it < 2; ++it) {
      int gi = it * 512 + tid;  // 0..1023 granules (128 t x 8 gd)
      int t = gi >> 3, gd = gi & 7;
      const float* px = x + (size_t)(b * TT + t0 + t) * DD + dc + gd * 8;
      float4 v0 = *(const float4*)px;
      float4 v1 = *(const float4*)(px + 4);
      bf16x8 pk;
      pk[0] = (short)f2bf(v0.x); pk[1] = (short)f2bf(v0.y);
      pk[2] = (short)f2bf(v0.z); pk[3] = (short)f2bf(v0.w);
      pk[4] = (short)f2bf(v1.x); pk[5] = (short)f2bf(v1.y);
      pk[6] = (short)f2bf(v1.z); pk[7] = (short)f2bf(v1.w);
      *(bf16x8*)(xs + t * 64 + ((gd ^ (t & 7)) << 3)) = pk;
      const int tg = t >> 3, tlo = t & 7;
#pragma unroll
      for (int j = 0; j < 8; ++j) {
        const int d = dc + gd * 8 + j;
        xT[d * 128 + ((tg ^ (d & 15)) << 3) + tlo] = (ushort)pk[j];
      }
    }
    // stage W chunk (coalesced): 512 threads cover 64 k x 8 granules
    {
      int k = tid >> 3, gd = tid & 7;
      bf16x8 v = *(const bf16x8*)(whT + (size_t)k * DD + dc + gd * 8);
      *(bf16x8*)(wsm + k * 64 + ((gd ^ (k & 7)) << 3)) = v;
    }
    __syncthreads();
#pragma unroll
    for (int kc = 0; kc < 2; ++kc) {
      const int gq = kc * 4 + q;
      bf16x8 bfv[4];
#pragma unroll
      for (int nt = 0; nt < 4; ++nt) {
        const int k = nt * 16 + l15;
        bfv[nt] = *(const bf16x8*)(wsm + k * 64 + ((gq ^ (k & 7)) << 3));
      }
      const int t = wave * 16 + l15;
      bf16x8 af = *(const bf16x8*)(xs + t * 64 + ((gq ^ (t & 7)) << 3));
#pragma unroll
      for (int nt = 0; nt < 4; ++nt)
        acc[nt] = __builtin_amdgcn_mfma_f32_16x16x32_bf16(af, bfv[nt], acc[nt], 0, 0, 0);
    }
    __syncthreads();
  }

  // softmax epilogue: rows t = wave*16 + q*4 + r; cols k = nt*16 + l15
  float bia[4];
#pragma unroll
  for (int nt = 0; nt < 4; ++nt) bia[nt] = bias[nt * 16 + l15];

  ushort au[4][4];
  float sw[4] = {0.f, 0.f, 0.f, 0.f};
#pragma unroll
  for (int r = 0; r < 4; ++r) {
    float l[4];
#pragma unroll
    for (int nt = 0; nt < 4; ++nt) l[nt] = acc[nt][r] + bia[nt];
    float m = fmaxf(fmaxf(l[0], l[1]), fmaxf(l[2], l[3]));
#pragma unroll
    for (int s = 1; s <= 8; s <<= 1) m = fmaxf(m, __shfl_xor(m, s));
    float e[4];
#pragma unroll
    for (int nt = 0; nt < 4; ++nt) e[nt] = __expf(l[nt] - m);
    float ssum = e[0] + e[1] + e[2] + e[3];
#pragma unroll
    for (int s = 1; s <= 8; s <<= 1) ssum += __shfl_xor(ssum, s);
    float inv = 1.f / ssum;
#pragma unroll
    for (int nt = 0; nt < 4; ++nt) {
      ushort u = f2bf(e[nt] * inv);
      au[nt][r] = u;
      sw[nt] += bf2f(u);
    }
  }
#pragma unroll
  for (int nt = 0; nt < 4; ++nt) {
    float s = sw[nt];
    s += __shfl_xor(s, 16);
    s += __shfl_xor(s, 32);
    if (q == 0) atomicAdd(sum_w + b * KK + nt * 16 + l15, s);
  }

  // xs is dead; reuse the buffer as aTl. Barrier first: other waves may
  // still be in their last phase-A MFMA reading xs.
  __syncthreads();
#pragma unroll
  for (int nt = 0; nt < 4; ++nt)
#pragma unroll
    for (int r = 0; r < 4; ++r) {
      const int k = nt * 16 + l15;
      const int t = wave * 16 + q * 4 + r;
      aTl[k * 128 + (((t >> 3) ^ (k & 15)) << 3) + (t & 7)] = au[nt][r];
    }
  __syncthreads();

  // ---------- phase B: xagg[k][d] = aT @ x, all from LDS ----------
  f32x4 accB[4][4];
#pragma unroll
  for (int mk = 0; mk < 4; ++mk)
#pragma unroll
    for (int nd = 0; nd < 4; ++nd)
#pragma unroll
      for (int r = 0; r < 4; ++r) accB[mk][nd][r] = 0.f;

#pragma unroll
  for (int kc = 0; kc < 4; ++kc) {
    const int g = kc * 4 + q;
    bf16x8 afr[4], bfr[4];
#pragma unroll
    for (int mk = 0; mk < 4; ++mk) {
      const int k = mk * 16 + l15;
      afr[mk] = *(const bf16x8*)(aTl + k * 128 + ((g ^ (k & 15)) << 3));
    }
#pragma unroll
    for (int nd = 0; nd < 4; ++nd) {
      const int d = wave * 64 + nd * 16 + l15;
      bfr[nd] = *(const bf16x8*)(xT + d * 128 + ((g ^ (d & 15)) << 3));
    }
#pragma unroll
    for (int mk = 0; mk < 4; ++mk)
#pragma unroll
      for (int nd = 0; nd < 4; ++nd)
        accB[mk][nd] =
            __builtin_amdgcn_mfma_f32_16x16x32_bf16(afr[mk], bfr[nd], accB[mk][nd], 0, 0, 0);
  }
  // write: row k = mk*16 + q*4 + r, col d = wave*64 + nd*16 + l15
#pragma unroll
  for (int mk = 0; mk < 4; ++mk)
#pragma unroll
    for (int nd = 0; nd < 4; ++nd)
#pragma unroll
      for (int r = 0; r < 4; ++r) {
        const int k = mk * 16 + q * 4 + r;
        const int d = wave * 64 + nd * 16 + l15;
        xaggP[(size_t)((tsp * 32 + b) * KK + k) * DD + d] = accB[mk][nd][r];
      }
}

// ---------------- K3a: sum 8 partials, residual, per-(b,k) sumsq ----------------
__global__ __launch_bounds__(128) void nv_k3a(
    const float* __restrict__ xaggP, float* __restrict__ full,
    const float* __restrict__ centers, const float* __restrict__ sum_w,
    float* __restrict__ s1) {
  const int k = blockIdx.x, b = blockIdx.y;
  const int tid = threadIdx.x;
  const float sw = sum_w[b * KK + k];
  float4 v = make_float4(0.f, 0.f, 0.f, 0.f);
#pragma unroll
  for (int sp = 0; sp < 8; ++sp) {
    float4 p = *((const float4*)(xaggP + (size_t)((sp * 32 + b) * KK + k) * DD) + tid);
    v.x += p.x; v.y += p.y; v.z += p.z; v.w += p.w;
  }
  float4 c = *((const float4*)(centers + (size_t)k * DD) + tid);
  v.x = fmaf(-sw, c.x, v.x);
  v.y = fmaf(-sw, c.y, v.y);
  v.z = fmaf(-sw, c.z, v.z);
  v.w = fmaf(-sw, c.w, v.w);
  *((float4*)(full + (size_t)(b * KK + k) * DD) + tid) = v;
  float ss = v.x * v.x + v.y * v.y + v.z * v.z + v.w * v.w;
#pragma unroll
  for (int s = 1; s <= 32; s <<= 1) ss += __shfl_xor(ss, s);
  __shared__ float red[2];
  if ((tid & 63) == 0) red[tid >> 6] = ss;
  __syncthreads();
  if (tid == 0) s1[b * KK + k] = red[0] + red[1];
}

// ---------------- K3c: scale + transpose -> fullT[r][b] (K3b folded in) ----------------
// block (k, dchunk of 128): recompute per-b second-norm sum from s1 (8 KB,
// L2-hot), then stage scaled [32 b][128 d] to LDS, write [128 d][32 b].
__global__ __launch_bounds__(256) void nv_k3c(const float* __restrict__ full,
                                              const float* __restrict__ s1,
                                              float* __restrict__ fullT) {
  const int k = blockIdx.x, d0 = blockIdx.y * 128;
  const int tid = threadIdx.x;
  __shared__ float ls[32 * 132];  // [b][d], pad 132
  __shared__ float s2s[32];

  {
    int bb = tid >> 3, k8 = tid & 7;
    float p = 0.f;
#pragma unroll
    for (int i = 0; i < 8; ++i) {
      float r = s1[bb * KK + k8 * 8 + i];
      p += r / fmaxf(r, EPSF);
    }
    p += __shfl_xor(p, 1);
    p += __shfl_xor(p, 2);
    p += __shfl_xor(p, 4);
    if (k8 == 0) s2s[bb] = rsqrtf(fmaxf(p, EPSF));
  }
  __syncthreads();

#pragma unroll
  for (int it = 0; it < 4; ++it) {
    int fi = it * 256 + tid;  // 1024 float4s
    int b = fi >> 5, dg = fi & 31;
    float r = s1[b * KK + k];
    float sc = rsqrtf(fmaxf(r, EPSF)) * s2s[b];
    float4 v = *((const float4*)(full + (size_t)(b * KK + k) * DD + d0) + dg);
    v.x *= sc; v.y *= sc; v.z *= sc; v.w *= sc;
    *(float4*)(ls + b * 132 + dg * 4) = v;
  }
  __syncthreads();
#pragma unroll
  for (int it = 0; it < 4; ++it) {
    int fo = it * 256 + tid;  // 1024 float4s
    int d = fo >> 3, bq = fo & 7;
    float4 v;
    v.x = ls[(bq * 4 + 0) * 132 + d];
    v.y = ls[(bq * 4 + 1) * 132 + d];
    v.z = ls[(bq * 4 + 2) * 132 + d];
    v.w = ls[(bq * 4 + 3) * 132 + d];
    *(float4*)(fullT + (size_t)(k * DD + d0 + d) * 32 + bq * 4) = v;
  }
}

// ---------------- K4: GEMV-bundle, 128-row k-span, high occupancy ----------------
// grid (4 strips, 256 ksp) = 1024 blocks (~4 blocks/CU resident capacity).
// Each block: stage fst 128x32 (16 KB), 4 waves x 32 k-rows, 4-deep rv pipe.
__global__ __launch_bounds__(256) void nv_k4(
    const float* __restrict__ fullT, const float* __restrict__ reduc,
    float* __restrict__ outP) {
  const int strip = blockIdx.x;  // 4
  const int ksp = blockIdx.y;    // 256
  const int tid = threadIdx.x;
  const int wave = tid >> 6, lane = tid & 63;
  const int c0 = strip * 256 + lane * 4;
  const int kblk = ksp * 128;

  __shared__ float fst[128 * 32];  // [k_local][b] 16 KB; reused as red[32][...]
  __shared__ float red[32 * 256];  // 32 KB reduction buffer

#pragma unroll
  for (int it = 0; it < 4; ++it) {
    int f4 = it * 256 + tid;
    *(float4*)(fst + f4 * 4) = *(const float4*)(fullT + (size_t)kblk * 32 + f4 * 4);
  }
  __syncthreads();

  float4 acc[32];
#pragma unroll
  for (int b = 0; b < 32; ++b) acc[b] = make_float4(0.f, 0.f, 0.f, 0.f);

  const int kw = wave * 32;
  for (int kk = 0; kk < 32; kk += 4) {
    float4 rv[4];
#pragma unroll
    for (int j = 0; j < 4; ++j)
      rv[j] = *(const float4*)(reduc + (size_t)(kblk + kw + kk + j) * OO + c0);
#pragma unroll
    for (int j = 0; j < 4; ++j) {
      const int kl = kw + kk + j;
#pragma unroll
      for (int b4 = 0; b4 < 8; ++b4) {
        float4 fv = *(const float4*)(fst + kl * 32 + b4 * 4);
        acc[b4 * 4 + 0].x = fmaf(fv.x, rv[j].x, acc[b4 * 4 + 0].x);
        acc[b4 * 4 + 0].y = fmaf(fv.x, rv[j].y, acc[b4 * 4 + 0].y);
        acc[b4 * 4 + 0].z = fmaf(fv.x, rv[j].z, acc[b4 * 4 + 0].z);
        acc[b4 * 4 + 0].w = fmaf(fv.x, rv[j].w, acc[b4 * 4 + 0].w);
        acc[b4 * 4 + 1].x = fmaf(fv.y, rv[j].x, acc[b4 * 4 + 1].x);
        acc[b4 * 4 + 1].y = fmaf(fv.y, rv[j].y, acc[b4 * 4 + 1].y);
        acc[b4 * 4 + 1].z = fmaf(fv.y, rv[j].z, acc[b4 * 4 + 1].z);
        acc[b4 * 4 + 1].w = fmaf(fv.y, rv[j].w, acc[b4 * 4 + 1].w);
        acc[b4 * 4 + 2].x = fmaf(fv.z, rv[j].x, acc[b4 * 4 + 2].x);
        acc[b4 * 4 + 2].y = fmaf(fv.z, rv[j].y, acc[b4 * 4 + 2].y);
        acc[b4 * 4 + 2].z = fmaf(fv.z, rv[j].z, acc[b4 * 4 + 2].z);
        acc[b4 * 4 + 2].w = fmaf(fv.z, rv[j].w, acc[b4 * 4 + 2].w);
        acc[b4 * 4 + 3].x = fmaf(fv.w, rv[j].x, acc[b4 * 4 + 3].x);
        acc[b4 * 4 + 3].y = fmaf(fv.w, rv[j].y, acc[b4 * 4 + 3].y);
        acc[b4 * 4 + 3].z = fmaf(fv.w, rv[j].z, acc[b4 * 4 + 3].z);
        acc[b4 * 4 + 3].w = fmaf(fv.w, rv[j].w, acc[b4 * 4 + 3].w);
      }
    }
  }

  __syncthreads();
  for (int w = 0; w < 4; ++w) {
    if (wave == w) {
      if (w == 0) {
#pragma unroll
        for (int b = 0; b < 32; ++b)
          *(float4*)(red + b * 256 + lane * 4) = acc[b];
      } else {
#pragma unroll
        for (int b = 0; b < 32; ++b) {
          float4 v = *(float4*)(red + b * 256 + lane * 4);
          v.x += acc[b].x; v.y += acc[b].y; v.z += acc[b].z; v.w += acc[b].w;
          *(float4*)(red + b * 256 + lane * 4) = v;
        }
      }
    }
    __syncthreads();
  }

#pragma unroll
  for (int it = 0; it < 8; ++it) {
    int f4 = it * 256 + tid;
    int b = f4 >> 6, cg = f4 & 63;
    *(float4*)(outP + ((size_t)(ksp * 32 + b) * OO) + strip * 256 + cg * 4) =
        *(const float4*)(red + b * 256 + cg * 4);
  }
}

// ---------------- K5: out = sum over 256 k-splits ----------------
__global__ __launch_bounds__(128) void nv_k5(const float* __restrict__ outP,
                                             float* __restrict__ out) {
  const int idx = blockIdx.x * 128 + threadIdx.x;  // 0..32767
  float s = 0.f;
#pragma unroll 8
  for (int sp = 0; sp < 256; ++sp) s += outP[(size_t)sp * 32768 + idx];
  out[idx] = s;
}

extern "C" void kernel_launch(void* const* d_in, const int* in_sizes, int n_in,
                              void* d_out, int out_size, void* d_ws, size_t ws_size,
                              hipStream_t stream) {
  const float* x = (const float*)d_in[0];
  const float* weight = (const float*)d_in[1];
  const float* bias = (const float*)d_in[2];
  const float* centers = (const float*)d_in[3];
  const float* reduc = (const float*)d_in[4];
  float* out = (float*)d_out;
  float* ws = (float*)d_ws;

  float* xaggP = ws;                          // [0, 8M)
  float* full = ws + 8388608;                 // [8M, 9M)
  float* fullT = ws + 9437184;                // [9M, 10M)
  float* outP = ws + 10485760;                // [10M, 18M)
  ushort* whT = (ushort*)(ws + 18874368);     // 32768 ushorts
  float* sum_w = ws + 18890752;
  float* s1 = sum_w + 2048;

  nv_k0<<<136, 256, 0, stream>>>(weight, whT, sum_w);
  nv_k12<<<dim3(8, 32), 512, 0, stream>>>(x, whT, bias, xaggP, sum_w);
  nv_k3a<<<dim3(64, 32), 128, 0, stream>>>(xaggP, full, centers, sum_w, s1);
  nv_k3c<<<dim3(64, 4), 256, 0, stream>>>(full, s1, fullT);
  nv_k4<<<dim3(4, 256), 256, 0, stream>>>(fullT, reduc, outP);
  nv_k5<<<256, 128, 0, stream>>>(outP, out);
}

// Round 5
// 279.205 us; speedup vs baseline: 1.0508x; 1.0261x over previous
//
#include <hip/hip_runtime.h>
#include <math.h>

#define TT 1024
#define DD 512
#define KK 64
#define OO 1024
#define EPSF 1e-12f

typedef __attribute__((ext_vector_type(8))) short bf16x8;
typedef __attribute__((ext_vector_type(4))) float f32x4;

__device__ __forceinline__ ushort f2bf(float f) {
  unsigned u = __float_as_uint(f);
  u = (u + 0x7FFFu + ((u >> 16) & 1u)) >> 16;
  return (ushort)u;
}
__device__ __forceinline__ float bf2f(ushort h) {
  return __uint_as_float(((unsigned)h) << 16);
}

// ws layout (float units):
//  xaggP  f32 [8][32][64][512] = 8388608 @ 0
//  full   f32 [32][64*512]     = 1048576 @ 8388608
//  fullT  f32 [32768][32]      = 1048576 @ 9437184
//  outP   f32 [128][32][1024]  = 4194304 @ 10485760
//  whT    bf16[64][512]        = 16384 f @ 14680064
//  sum_w  @ 14696448 ; s1 +2048

// ---------------- K0: whT[k][d] <- weight[d][k]; zero sum_w ----------------
__global__ __launch_bounds__(256) void nv_k0(const float* __restrict__ w,
                                             ushort* __restrict__ whT,
                                             float* __restrict__ sum_w) {
  int idx = blockIdx.x * 256 + threadIdx.x;
  if (idx < 32768) {
    int d = idx >> 6, k = idx & 63;
    whT[(size_t)k * DD + d] = f2bf(w[idx]);
  } else if (idx < 32768 + 2048) {
    sum_w[idx - 32768] = 0.f;
  }
}

// ---------------- K12: fused softmax-assign + aggregate ----------------
// block: (tsp, b), t-tile = 128, 8 waves. Phase A: COALESCED staged loads
// (x -> xs, whT -> wsm per 64-d chunk), MFMA frags from LDS; the same x
// registers are also deposited transposed into the persistent xT tile, so
// x is read from HBM exactly once. Phase B runs entirely out of xT + aTl.
// LDS: xT 128K + union{xs,aTl} 16K + wsm 8K = 152 KB.
__global__ __launch_bounds__(512) void nv_k12(
    const float* __restrict__ x, const ushort* __restrict__ whT,
    const float* __restrict__ bias, float* __restrict__ xaggP,
    float* __restrict__ sum_w) {
  const int tsp = blockIdx.x, b = blockIdx.y;
  const int t0 = tsp * 128;
  const int tid = threadIdx.x;
  const int wave = tid >> 6, lane = tid & 63, l15 = lane & 15, q = lane >> 4;

  __shared__ ushort xT[512 * 128];  // [d][t-granule], slot g^(d&15)   128 KB
  __shared__ ushort xsa[128 * 64];  // phase A: xs[t][dg]; later aTl[k][tg] 16 KB
  __shared__ ushort wsm[64 * 64];   // [k][d-granule], slot g^(k&7)      8 KB
  ushort* xs = xsa;
  ushort* aTl = xsa;

  // ---------- phase A: logits, x read ONCE, all loads coalesced ----------
  f32x4 acc[4];
#pragma unroll
  for (int nt = 0; nt < 4; ++nt)
#pragma unroll
    for (int r = 0; r < 4; ++r) acc[nt][r] = 0.f;

  for (int dc = 0; dc < DD; dc += 64) {
    // stage x chunk (coalesced) + deposit transposed copy into xT
#pragma unroll
    for (int it = 0; it < 2; ++it) {
      int gi = it * 512 + tid;  // 0..1023 granules (128 t x 8 gd)
      int t = gi >> 3, gd = gi & 7;
      const float* px = x + (size_t)(b * TT + t0 + t) * DD + dc + gd * 8;
      float4 v0 = *(const float4*)px;
      float4 v1 = *(const float4*)(px + 4);
      bf16x8 pk;
      pk[0] = (short)f2bf(v0.x); pk[1] = (short)f2bf(v0.y);
      pk[2] = (short)f2bf(v0.z); pk[3] = (short)f2bf(v0.w);
      pk[4] = (short)f2bf(v1.x); pk[5] = (short)f2bf(v1.y);
      pk[6] = (short)f2bf(v1.z); pk[7] = (short)f2bf(v1.w);
      *(bf16x8*)(xs + t * 64 + ((gd ^ (t & 7)) << 3)) = pk;
      const int tg = t >> 3, tlo = t & 7;
#pragma unroll
      for (int j = 0; j < 8; ++j) {
        const int d = dc + gd * 8 + j;
        xT[d * 128 + ((tg ^ (d & 15)) << 3) + tlo] = (ushort)pk[j];
      }
    }
    // stage W chunk (coalesced): 512 threads cover 64 k x 8 granules
    {
      int k = tid >> 3, gd = tid & 7;
      bf16x8 v = *(const bf16x8*)(whT + (size_t)k * DD + dc + gd * 8);
      *(bf16x8*)(wsm + k * 64 + ((gd ^ (k & 7)) << 3)) = v;
    }
    __syncthreads();
#pragma unroll
    for (int kc = 0; kc < 2; ++kc) {
      const int gq = kc * 4 + q;
      bf16x8 bfv[4];
#pragma unroll
      for (int nt = 0; nt < 4; ++nt) {
        const int k = nt * 16 + l15;
        bfv[nt] = *(const bf16x8*)(wsm + k * 64 + ((gq ^ (k & 7)) << 3));
      }
      const int t = wave * 16 + l15;
      bf16x8 af = *(const bf16x8*)(xs + t * 64 + ((gq ^ (t & 7)) << 3));
#pragma unroll
      for (int nt = 0; nt < 4; ++nt)
        acc[nt] = __builtin_amdgcn_mfma_f32_16x16x32_bf16(af, bfv[nt], acc[nt], 0, 0, 0);
    }
    __syncthreads();
  }

  // softmax epilogue: rows t = wave*16 + q*4 + r; cols k = nt*16 + l15
  float bia[4];
#pragma unroll
  for (int nt = 0; nt < 4; ++nt) bia[nt] = bias[nt * 16 + l15];

  ushort au[4][4];
  float sw[4] = {0.f, 0.f, 0.f, 0.f};
#pragma unroll
  for (int r = 0; r < 4; ++r) {
    float l[4];
#pragma unroll
    for (int nt = 0; nt < 4; ++nt) l[nt] = acc[nt][r] + bia[nt];
    float m = fmaxf(fmaxf(l[0], l[1]), fmaxf(l[2], l[3]));
#pragma unroll
    for (int s = 1; s <= 8; s <<= 1) m = fmaxf(m, __shfl_xor(m, s));
    float e[4];
#pragma unroll
    for (int nt = 0; nt < 4; ++nt) e[nt] = __expf(l[nt] - m);
    float ssum = e[0] + e[1] + e[2] + e[3];
#pragma unroll
    for (int s = 1; s <= 8; s <<= 1) ssum += __shfl_xor(ssum, s);
    float inv = 1.f / ssum;
#pragma unroll
    for (int nt = 0; nt < 4; ++nt) {
      ushort u = f2bf(e[nt] * inv);
      au[nt][r] = u;
      sw[nt] += bf2f(u);
    }
  }
#pragma unroll
  for (int nt = 0; nt < 4; ++nt) {
    float s = sw[nt];
    s += __shfl_xor(s, 16);
    s += __shfl_xor(s, 32);
    if (q == 0) atomicAdd(sum_w + b * KK + nt * 16 + l15, s);
  }

  // xs is dead; reuse the buffer as aTl. Barrier first: other waves may
  // still be in their last phase-A MFMA reading xs.
  __syncthreads();
#pragma unroll
  for (int nt = 0; nt < 4; ++nt)
#pragma unroll
    for (int r = 0; r < 4; ++r) {
      const int k = nt * 16 + l15;
      const int t = wave * 16 + q * 4 + r;
      aTl[k * 128 + (((t >> 3) ^ (k & 15)) << 3) + (t & 7)] = au[nt][r];
    }
  __syncthreads();

  // ---------- phase B: xagg[k][d] = aT @ x, all from LDS ----------
  f32x4 accB[4][4];
#pragma unroll
  for (int mk = 0; mk < 4; ++mk)
#pragma unroll
    for (int nd = 0; nd < 4; ++nd)
#pragma unroll
      for (int r = 0; r < 4; ++r) accB[mk][nd][r] = 0.f;

#pragma unroll
  for (int kc = 0; kc < 4; ++kc) {
    const int g = kc * 4 + q;
    bf16x8 afr[4], bfr[4];
#pragma unroll
    for (int mk = 0; mk < 4; ++mk) {
      const int k = mk * 16 + l15;
      afr[mk] = *(const bf16x8*)(aTl + k * 128 + ((g ^ (k & 15)) << 3));
    }
#pragma unroll
    for (int nd = 0; nd < 4; ++nd) {
      const int d = wave * 64 + nd * 16 + l15;
      bfr[nd] = *(const bf16x8*)(xT + d * 128 + ((g ^ (d & 15)) << 3));
    }
#pragma unroll
    for (int mk = 0; mk < 4; ++mk)
#pragma unroll
      for (int nd = 0; nd < 4; ++nd)
        accB[mk][nd] =
            __builtin_amdgcn_mfma_f32_16x16x32_bf16(afr[mk], bfr[nd], accB[mk][nd], 0, 0, 0);
  }
  // write: row k = mk*16 + q*4 + r, col d = wave*64 + nd*16 + l15
#pragma unroll
  for (int mk = 0; mk < 4; ++mk)
#pragma unroll
    for (int nd = 0; nd < 4; ++nd)
#pragma unroll
      for (int r = 0; r < 4; ++r) {
        const int k = mk * 16 + q * 4 + r;
        const int d = wave * 64 + nd * 16 + l15;
        xaggP[(size_t)((tsp * 32 + b) * KK + k) * DD + d] = accB[mk][nd][r];
      }
}

// ---------------- K3a: sum 8 partials, residual, per-(b,k) sumsq ----------------
__global__ __launch_bounds__(128) void nv_k3a(
    const float* __restrict__ xaggP, float* __restrict__ full,
    const float* __restrict__ centers, const float* __restrict__ sum_w,
    float* __restrict__ s1) {
  const int k = blockIdx.x, b = blockIdx.y;
  const int tid = threadIdx.x;
  const float sw = sum_w[b * KK + k];
  float4 v = make_float4(0.f, 0.f, 0.f, 0.f);
#pragma unroll
  for (int sp = 0; sp < 8; ++sp) {
    float4 p = *((const float4*)(xaggP + (size_t)((sp * 32 + b) * KK + k) * DD) + tid);
    v.x += p.x; v.y += p.y; v.z += p.z; v.w += p.w;
  }
  float4 c = *((const float4*)(centers + (size_t)k * DD) + tid);
  v.x = fmaf(-sw, c.x, v.x);
  v.y = fmaf(-sw, c.y, v.y);
  v.z = fmaf(-sw, c.z, v.z);
  v.w = fmaf(-sw, c.w, v.w);
  *((float4*)(full + (size_t)(b * KK + k) * DD) + tid) = v;
  float ss = v.x * v.x + v.y * v.y + v.z * v.z + v.w * v.w;
#pragma unroll
  for (int s = 1; s <= 32; s <<= 1) ss += __shfl_xor(ss, s);
  __shared__ float red[2];
  if ((tid & 63) == 0) red[tid >> 6] = ss;
  __syncthreads();
  if (tid == 0) s1[b * KK + k] = red[0] + red[1];
}

// ---------------- K3c: scale + transpose -> fullT[r][b] (K3b folded in) ----------------
// block (k, dchunk of 128): recompute per-b second-norm sum from s1 (8 KB,
// L2-hot), then stage scaled [32 b][128 d] to LDS, write [128 d][32 b].
__global__ __launch_bounds__(256) void nv_k3c(const float* __restrict__ full,
                                              const float* __restrict__ s1,
                                              float* __restrict__ fullT) {
  const int k = blockIdx.x, d0 = blockIdx.y * 128;
  const int tid = threadIdx.x;
  __shared__ float ls[32 * 132];  // [b][d], pad 132
  __shared__ float s2s[32];

  {
    int bb = tid >> 3, k8 = tid & 7;
    float p = 0.f;
#pragma unroll
    for (int i = 0; i < 8; ++i) {
      float r = s1[bb * KK + k8 * 8 + i];
      p += r / fmaxf(r, EPSF);
    }
    p += __shfl_xor(p, 1);
    p += __shfl_xor(p, 2);
    p += __shfl_xor(p, 4);
    if (k8 == 0) s2s[bb] = rsqrtf(fmaxf(p, EPSF));
  }
  __syncthreads();

#pragma unroll
  for (int it = 0; it < 4; ++it) {
    int fi = it * 256 + tid;  // 1024 float4s
    int b = fi >> 5, dg = fi & 31;
    float r = s1[b * KK + k];
    float sc = rsqrtf(fmaxf(r, EPSF)) * s2s[b];
    float4 v = *((const float4*)(full + (size_t)(b * KK + k) * DD + d0) + dg);
    v.x *= sc; v.y *= sc; v.z *= sc; v.w *= sc;
    *(float4*)(ls + b * 132 + dg * 4) = v;
  }
  __syncthreads();
#pragma unroll
  for (int it = 0; it < 4; ++it) {
    int fo = it * 256 + tid;  // 1024 float4s
    int d = fo >> 3, bq = fo & 7;
    float4 v;
    v.x = ls[(bq * 4 + 0) * 132 + d];
    v.y = ls[(bq * 4 + 1) * 132 + d];
    v.z = ls[(bq * 4 + 2) * 132 + d];
    v.w = ls[(bq * 4 + 3) * 132 + d];
    *(float4*)(fullT + (size_t)(k * DD + d0 + d) * 32 + bq * 4) = v;
  }
}

// ---------------- K4 helper: one 4-row FMA batch ----------------
__device__ __forceinline__ void nv_k4_fmab(float4* acc, const float* fst,
                                           const float4* rv, int kbase) {
#pragma unroll
  for (int j = 0; j < 4; ++j) {
    const int kl = kbase + j;
#pragma unroll
    for (int b4 = 0; b4 < 8; ++b4) {
      float4 fv = *(const float4*)(fst + kl * 32 + b4 * 4);
      acc[b4 * 4 + 0].x = fmaf(fv.x, rv[j].x, acc[b4 * 4 + 0].x);
      acc[b4 * 4 + 0].y = fmaf(fv.x, rv[j].y, acc[b4 * 4 + 0].y);
      acc[b4 * 4 + 0].z = fmaf(fv.x, rv[j].z, acc[b4 * 4 + 0].z);
      acc[b4 * 4 + 0].w = fmaf(fv.x, rv[j].w, acc[b4 * 4 + 0].w);
      acc[b4 * 4 + 1].x = fmaf(fv.y, rv[j].x, acc[b4 * 4 + 1].x);
      acc[b4 * 4 + 1].y = fmaf(fv.y, rv[j].y, acc[b4 * 4 + 1].y);
      acc[b4 * 4 + 1].z = fmaf(fv.y, rv[j].z, acc[b4 * 4 + 1].z);
      acc[b4 * 4 + 1].w = fmaf(fv.y, rv[j].w, acc[b4 * 4 + 1].w);
      acc[b4 * 4 + 2].x = fmaf(fv.z, rv[j].x, acc[b4 * 4 + 2].x);
      acc[b4 * 4 + 2].y = fmaf(fv.z, rv[j].y, acc[b4 * 4 + 2].y);
      acc[b4 * 4 + 2].z = fmaf(fv.z, rv[j].z, acc[b4 * 4 + 2].z);
      acc[b4 * 4 + 2].w = fmaf(fv.z, rv[j].w, acc[b4 * 4 + 2].w);
      acc[b4 * 4 + 3].x = fmaf(fv.w, rv[j].x, acc[b4 * 4 + 3].x);
      acc[b4 * 4 + 3].y = fmaf(fv.w, rv[j].y, acc[b4 * 4 + 3].y);
      acc[b4 * 4 + 3].z = fmaf(fv.w, rv[j].z, acc[b4 * 4 + 3].z);
      acc[b4 * 4 + 3].w = fmaf(fv.w, rv[j].w, acc[b4 * 4 + 3].w);
    }
  }
}

// ---------------- K4: GEMV-bundle, two-buffer register prefetch ----------------
// grid (4 strips, 128 ksp) — R2 geometry. Inner loop double-buffers the rv
// batches (rvA/rvB, static names per scratch rule): batch t+1's 4 loads are
// issued BEFORE batch t's FMA burst, so loads stay in flight across compute.
__global__ __launch_bounds__(256) void nv_k4(
    const float* __restrict__ fullT, const float* __restrict__ reduc,
    float* __restrict__ outP) {
  const int strip = blockIdx.x;  // 4
  const int ksp = blockIdx.y;    // 128
  const int tid = threadIdx.x;
  const int wave = tid >> 6, lane = tid & 63;
  const int c0 = strip * 256 + lane * 4;
  const int kblk = ksp * 256;

  __shared__ float fst[256 * 32];  // [k_local][b]; reused as red[32][256]

#pragma unroll
  for (int it = 0; it < 8; ++it) {
    int f4 = it * 256 + tid;
    *(float4*)(fst + f4 * 4) = *(const float4*)(fullT + (size_t)kblk * 32 + f4 * 4);
  }
  __syncthreads();

  float4 acc[32];
#pragma unroll
  for (int b = 0; b < 32; ++b) acc[b] = make_float4(0.f, 0.f, 0.f, 0.f);

  const int kw = wave * 64;
  const float* rbase = reduc + (size_t)(kblk + kw) * OO + c0;

  float4 rvA[4], rvB[4];
#pragma unroll
  for (int j = 0; j < 4; ++j)
    rvA[j] = *(const float4*)(rbase + (size_t)j * OO);

  for (int kk = 0; kk < 64; kk += 8) {
#pragma unroll
    for (int j = 0; j < 4; ++j)
      rvB[j] = *(const float4*)(rbase + (size_t)(kk + 4 + j) * OO);
    nv_k4_fmab(acc, fst, rvA, kw + kk);
    if (kk + 8 < 64) {
#pragma unroll
      for (int j = 0; j < 4; ++j)
        rvA[j] = *(const float4*)(rbase + (size_t)(kk + 8 + j) * OO);
    }
    nv_k4_fmab(acc, fst, rvB, kw + kk + 4);
  }

  __syncthreads();
  for (int w = 0; w < 4; ++w) {
    if (wave == w) {
      if (w == 0) {
#pragma unroll
        for (int b = 0; b < 32; ++b)
          *(float4*)(fst + b * 256 + lane * 4) = acc[b];
      } else {
#pragma unroll
        for (int b = 0; b < 32; ++b) {
          float4 v = *(float4*)(fst + b * 256 + lane * 4);
          v.x += acc[b].x; v.y += acc[b].y; v.z += acc[b].z; v.w += acc[b].w;
          *(float4*)(fst + b * 256 + lane * 4) = v;
        }
      }
    }
    __syncthreads();
  }

#pragma unroll
  for (int it = 0; it < 8; ++it) {
    int f4 = it * 256 + tid;
    int b = f4 >> 6, cg = f4 & 63;
    *(float4*)(outP + ((size_t)(ksp * 32 + b) * OO) + strip * 256 + cg * 4) =
        *(const float4*)(fst + b * 256 + cg * 4);
  }
}

// ---------------- K5: out = sum over 128 k-splits ----------------
__global__ __launch_bounds__(128) void nv_k5(const float* __restrict__ outP,
                                             float* __restrict__ out) {
  const int idx = blockIdx.x * 128 + threadIdx.x;  // 0..32767
  float s = 0.f;
#pragma unroll 8
  for (int sp = 0; sp < 128; ++sp) s += outP[(size_t)sp * 32768 + idx];
  out[idx] = s;
}

extern "C" void kernel_launch(void* const* d_in, const int* in_sizes, int n_in,
                              void* d_out, int out_size, void* d_ws, size_t ws_size,
                              hipStream_t stream) {
  const float* x = (const float*)d_in[0];
  const float* weight = (const float*)d_in[1];
  const float* bias = (const float*)d_in[2];
  const float* centers = (const float*)d_in[3];
  const float* reduc = (const float*)d_in[4];
  float* out = (float*)d_out;
  float* ws = (float*)d_ws;

  float* xaggP = ws;                          // [0, 8M)
  float* full = ws + 8388608;                 // [8M, 9M)
  float* fullT = ws + 9437184;                // [9M, 10M)
  float* outP = ws + 10485760;                // [10M, 14M)
  ushort* whT = (ushort*)(ws + 14680064);     // 32768 ushorts
  float* sum_w = ws + 14696448;
  float* s1 = sum_w + 2048;

  nv_k0<<<136, 256, 0, stream>>>(weight, whT, sum_w);
  nv_k12<<<dim3(8, 32), 512, 0, stream>>>(x, whT, bias, xaggP, sum_w);
  nv_k3a<<<dim3(64, 32), 128, 0, stream>>>(xaggP, full, centers, sum_w, s1);
  nv_k3c<<<dim3(64, 4), 256, 0, stream>>>(full, s1, fullT);
  nv_k4<<<dim3(4, 128), 256, 0, stream>>>(fullT, reduc, outP);
  nv_k5<<<256, 128, 0, stream>>>(outP, out);
}

// Round 7
// 267.787 us; speedup vs baseline: 1.0956x; 1.0426x over previous
//
#include <hip/hip_runtime.h>
#include <math.h>

#define TT 1024
#define DD 512
#define KK 64
#define OO 1024
#define EPSF 1e-12f

typedef __attribute__((ext_vector_type(8))) short bf16x8;
typedef __attribute__((ext_vector_type(4))) float f32x4;

__device__ __forceinline__ ushort f2bf(float f) {
  unsigned u = __float_as_uint(f);
  u = (u + 0x7FFFu + ((u >> 16) & 1u)) >> 16;
  return (ushort)u;
}
__device__ __forceinline__ float bf2f(ushort h) {
  return __uint_as_float(((unsigned)h) << 16);
}

// ws layout (float units):
//  xaggP  f32 [8][32][64][512] = 8388608 @ 0
//  full   f32 [32][32768]      = 1048576 @ 8388608
//  outP   f32 [32][32][1024]   = 1048576 @ 9437184
//  whT    bf16[64][512]        = 16384 f @ 10485760
//  sum_w  @ 10502144 ; s1 +2048 ; scale +4096

// ---------------- K0: whT[k][d] <- weight[d][k]; zero sum_w ----------------
__global__ __launch_bounds__(256) void nv_k0(const float* __restrict__ w,
                                             ushort* __restrict__ whT,
                                             float* __restrict__ sum_w) {
  int idx = blockIdx.x * 256 + threadIdx.x;
  if (idx < 32768) {
    int d = idx >> 6, k = idx & 63;
    whT[(size_t)k * DD + d] = f2bf(w[idx]);
  } else if (idx < 32768 + 2048) {
    sum_w[idx - 32768] = 0.f;
  }
}

// ---------------- K12: fused softmax-assign + aggregate (unchanged) ----------------
__global__ __launch_bounds__(512) void nv_k12(
    const float* __restrict__ x, const ushort* __restrict__ whT,
    const float* __restrict__ bias, float* __restrict__ xaggP,
    float* __restrict__ sum_w) {
  const int tsp = blockIdx.x, b = blockIdx.y;
  const int t0 = tsp * 128;
  const int tid = threadIdx.x;
  const int wave = tid >> 6, lane = tid & 63, l15 = lane & 15, q = lane >> 4;

  __shared__ ushort xT[512 * 128];  // [d][t-granule], slot g^(d&15)   128 KB
  __shared__ ushort xsa[128 * 64];  // phase A: xs[t][dg]; later aTl[k][tg] 16 KB
  __shared__ ushort wsm[64 * 64];   // [k][d-granule], slot g^(k&7)      8 KB
  ushort* xs = xsa;
  ushort* aTl = xsa;

  f32x4 acc[4];
#pragma unroll
  for (int nt = 0; nt < 4; ++nt)
#pragma unroll
    for (int r = 0; r < 4; ++r) acc[nt][r] = 0.f;

  for (int dc = 0; dc < DD; dc += 64) {
#pragma unroll
    for (int it = 0; it < 2; ++it) {
      int gi = it * 512 + tid;
      int t = gi >> 3, gd = gi & 7;
      const float* px = x + (size_t)(b * TT + t0 + t) * DD + dc + gd * 8;
      float4 v0 = *(const float4*)px;
      float4 v1 = *(const float4*)(px + 4);
      bf16x8 pk;
      pk[0] = (short)f2bf(v0.x); pk[1] = (short)f2bf(v0.y);
      pk[2] = (short)f2bf(v0.z); pk[3] = (short)f2bf(v0.w);
      pk[4] = (short)f2bf(v1.x); pk[5] = (short)f2bf(v1.y);
      pk[6] = (short)f2bf(v1.z); pk[7] = (short)f2bf(v1.w);
      *(bf16x8*)(xs + t * 64 + ((gd ^ (t & 7)) << 3)) = pk;
      const int tg = t >> 3, tlo = t & 7;
#pragma unroll
      for (int j = 0; j < 8; ++j) {
        const int d = dc + gd * 8 + j;
        xT[d * 128 + ((tg ^ (d & 15)) << 3) + tlo] = (ushort)pk[j];
      }
    }
    {
      int k = tid >> 3, gd = tid & 7;
      bf16x8 v = *(const bf16x8*)(whT + (size_t)k * DD + dc + gd * 8);
      *(bf16x8*)(wsm + k * 64 + ((gd ^ (k & 7)) << 3)) = v;
    }
    __syncthreads();
#pragma unroll
    for (int kc = 0; kc < 2; ++kc) {
      const int gq = kc * 4 + q;
      bf16x8 bfv[4];
#pragma unroll
      for (int nt = 0; nt < 4; ++nt) {
        const int k = nt * 16 + l15;
        bfv[nt] = *(const bf16x8*)(wsm + k * 64 + ((gq ^ (k & 7)) << 3));
      }
      const int t = wave * 16 + l15;
      bf16x8 af = *(const bf16x8*)(xs + t * 64 + ((gq ^ (t & 7)) << 3));
#pragma unroll
      for (int nt = 0; nt < 4; ++nt)
        acc[nt] = __builtin_amdgcn_mfma_f32_16x16x32_bf16(af, bfv[nt], acc[nt], 0, 0, 0);
    }
    __syncthreads();
  }

  float bia[4];
#pragma unroll
  for (int nt = 0; nt < 4; ++nt) bia[nt] = bias[nt * 16 + l15];

  ushort au[4][4];
  float sw[4] = {0.f, 0.f, 0.f, 0.f};
#pragma unroll
  for (int r = 0; r < 4; ++r) {
    float l[4];
#pragma unroll
    for (int nt = 0; nt < 4; ++nt) l[nt] = acc[nt][r] + bia[nt];
    float m = fmaxf(fmaxf(l[0], l[1]), fmaxf(l[2], l[3]));
#pragma unroll
    for (int s = 1; s <= 8; s <<= 1) m = fmaxf(m, __shfl_xor(m, s));
    float e[4];
#pragma unroll
    for (int nt = 0; nt < 4; ++nt) e[nt] = __expf(l[nt] - m);
    float ssum = e[0] + e[1] + e[2] + e[3];
#pragma unroll
    for (int s = 1; s <= 8; s <<= 1) ssum += __shfl_xor(ssum, s);
    float inv = 1.f / ssum;
#pragma unroll
    for (int nt = 0; nt < 4; ++nt) {
      ushort u = f2bf(e[nt] * inv);
      au[nt][r] = u;
      sw[nt] += bf2f(u);
    }
  }
#pragma unroll
  for (int nt = 0; nt < 4; ++nt) {
    float s = sw[nt];
    s += __shfl_xor(s, 16);
    s += __shfl_xor(s, 32);
    if (q == 0) atomicAdd(sum_w + b * KK + nt * 16 + l15, s);
  }

  __syncthreads();
#pragma unroll
  for (int nt = 0; nt < 4; ++nt)
#pragma unroll
    for (int r = 0; r < 4; ++r) {
      const int k = nt * 16 + l15;
      const int t = wave * 16 + q * 4 + r;
      aTl[k * 128 + (((t >> 3) ^ (k & 15)) << 3) + (t & 7)] = au[nt][r];
    }
  __syncthreads();

  f32x4 accB[4][4];
#pragma unroll
  for (int mk = 0; mk < 4; ++mk)
#pragma unroll
    for (int nd = 0; nd < 4; ++nd)
#pragma unroll
      for (int r = 0; r < 4; ++r) accB[mk][nd][r] = 0.f;

#pragma unroll
  for (int kc = 0; kc < 4; ++kc) {
    const int g = kc * 4 + q;
    bf16x8 afr[4], bfr[4];
#pragma unroll
    for (int mk = 0; mk < 4; ++mk) {
      const int k = mk * 16 + l15;
      afr[mk] = *(const bf16x8*)(aTl + k * 128 + ((g ^ (k & 15)) << 3));
    }
#pragma unroll
    for (int nd = 0; nd < 4; ++nd) {
      const int d = wave * 64 + nd * 16 + l15;
      bfr[nd] = *(const bf16x8*)(xT + d * 128 + ((g ^ (d & 15)) << 3));
    }
#pragma unroll
    for (int mk = 0; mk < 4; ++mk)
#pragma unroll
      for (int nd = 0; nd < 4; ++nd)
        accB[mk][nd] =
            __builtin_amdgcn_mfma_f32_16x16x32_bf16(afr[mk], bfr[nd], accB[mk][nd], 0, 0, 0);
  }
#pragma unroll
  for (int mk = 0; mk < 4; ++mk)
#pragma unroll
    for (int nd = 0; nd < 4; ++nd)
#pragma unroll
      for (int r = 0; r < 4; ++r) {
        const int k = mk * 16 + q * 4 + r;
        const int d = wave * 64 + nd * 16 + l15;
        xaggP[(size_t)((tsp * 32 + b) * KK + k) * DD + d] = accB[mk][nd][r];
      }
}

// ---------------- K3a: sum 8 partials, residual, per-(b,k) sumsq ----------------
__global__ __launch_bounds__(128) void nv_k3a(
    const float* __restrict__ xaggP, float* __restrict__ full,
    const float* __restrict__ centers, const float* __restrict__ sum_w,
    float* __restrict__ s1) {
  const int k = blockIdx.x, b = blockIdx.y;
  const int tid = threadIdx.x;
  const float sw = sum_w[b * KK + k];
  float4 v = make_float4(0.f, 0.f, 0.f, 0.f);
#pragma unroll
  for (int sp = 0; sp < 8; ++sp) {
    float4 p = *((const float4*)(xaggP + (size_t)((sp * 32 + b) * KK + k) * DD) + tid);
    v.x += p.x; v.y += p.y; v.z += p.z; v.w += p.w;
  }
  float4 c = *((const float4*)(centers + (size_t)k * DD) + tid);
  v.x = fmaf(-sw, c.x, v.x);
  v.y = fmaf(-sw, c.y, v.y);
  v.z = fmaf(-sw, c.z, v.z);
  v.w = fmaf(-sw, c.w, v.w);
  *((float4*)(full + (size_t)b * (KK * DD) + (size_t)k * DD) + tid) = v;
  float ss = v.x * v.x + v.y * v.y + v.z * v.z + v.w * v.w;
#pragma unroll
  for (int s = 1; s <= 32; s <<= 1) ss += __shfl_xor(ss, s);
  __shared__ float red[2];
  if ((tid & 63) == 0) red[tid >> 6] = ss;
  __syncthreads();
  if (tid == 0) s1[b * KK + k] = red[0] + red[1];
}

// ---------------- K3b: per-(b,k) combined scale (R0-verbatim) ----------------
__global__ __launch_bounds__(64) void nv_k3b(const float* __restrict__ s1,
                                             float* __restrict__ scale) {
  const int b = blockIdx.x, k = threadIdx.x;
  float r = s1[b * KK + k];
  float d1 = fmaxf(r, EPSF);
  float s2 = r / d1;
#pragma unroll
  for (int s = 1; s <= 32; s <<= 1) s2 += __shfl_xor(s2, s);
  scale[b * KK + k] = rsqrtf(d1) * rsqrtf(fmaxf(s2, EPSF));
}

// ---------------- K4: MFMA hi/lo GEMM: outP[ksp] = (full.*scale) @ reduc ----------------
// grid (16 osp, 32 ksp), 256 thr, 4 waves. K-span 1024 per block, K-step 64.
// A = full[b][r]*scale (32x64 per step, hi/lo bf16), B = reduc[r][o] (64x64,
// hi/lo bf16, transposed deposit). Fragment/swizzle math mirrors K12 phase A.
__global__ __launch_bounds__(256) void nv_k4(
    const float* __restrict__ full, const float* __restrict__ scale,
    const float* __restrict__ reduc, float* __restrict__ outP) {
  const int osp = blockIdx.x;  // 16
  const int ksp = blockIdx.y;  // 32
  const int tid = threadIdx.x;
  const int wave = tid >> 6, lane = tid & 63, l15 = lane & 15, q = lane >> 4;
  const int ob = osp * 64;
  const int r00 = ksp * 1024;

  __shared__ ushort rTh[64 * 64];  // B hi: [o][k-slot ((g^(o&7))<<3)+e]  8 KB
  __shared__ ushort rTl[64 * 64];  // B lo                                8 KB
  __shared__ ushort ahs[32 * 64];  // A hi: [b][k-slot ((g^(b&7))<<3)+e]  4 KB
  __shared__ ushort als[32 * 64];  // A lo                                4 KB
  __shared__ float scs[64];        // scale[b][ksp*2 + h], h=0,1

  if (tid < 64) scs[tid] = scale[(tid & 31) * KK + ksp * 2 + (tid >> 5)];

  // load assignments
  const int Br = tid >> 2, Bo = (tid & 3) * 16;          // B: row r-local, o-base
  const int Bg = Br >> 3, Be = Br & 7;                   // B granule/elem
  const int Ab = tid >> 3, Ak = (tid & 7) * 8;           // A: b-row, k-base
  const int Asl = ((tid & 7) ^ (Ab & 7)) << 3;           // A slot (granule = Ak>>3)

  const float* rbB = reduc + (size_t)(r00 + Br) * OO + ob + Bo;
  const float* rbA = full + (size_t)Ab * 32768 + r00 + Ak;

  f32x4 acc[2];
#pragma unroll
  for (int mt = 0; mt < 2; ++mt)
#pragma unroll
    for (int rr = 0; rr < 4; ++rr) acc[mt][rr] = 0.f;

  float4 bv0, bv1, bv2, bv3, av0, av1;
  bv0 = *(const float4*)(rbB + 0);
  bv1 = *(const float4*)(rbB + 4);
  bv2 = *(const float4*)(rbB + 8);
  bv3 = *(const float4*)(rbB + 12);
  av0 = *(const float4*)(rbA + 0);
  av1 = *(const float4*)(rbA + 4);

  for (int ks = 0; ks < 16; ++ks) {
    __syncthreads();  // previous step's fragment reads complete
    // ---- deposit B (transposed, hi/lo) ----
    {
      float vv[16] = {bv0.x, bv0.y, bv0.z, bv0.w, bv1.x, bv1.y, bv1.z, bv1.w,
                      bv2.x, bv2.y, bv2.z, bv2.w, bv3.x, bv3.y, bv3.z, bv3.w};
#pragma unroll
      for (int j = 0; j < 16; ++j) {
        const int o = Bo + j;
        const int sl = ((Bg ^ (o & 7)) << 3) + Be;
        float f = vv[j];
        ushort h = f2bf(f);
        rTh[o * 64 + sl] = h;
        rTl[o * 64 + sl] = f2bf(f - bf2f(h));
      }
    }
    // ---- deposit A (scaled, hi/lo, vector writes) ----
    {
      const float sc = scs[Ab + ((ks >> 3) << 5)];
      float aa[8] = {av0.x, av0.y, av0.z, av0.w, av1.x, av1.y, av1.z, av1.w};
      bf16x8 hi, lo;
#pragma unroll
      for (int e = 0; e < 8; ++e) {
        float f = aa[e] * sc;
        ushort h = f2bf(f);
        hi[e] = (short)h;
        lo[e] = (short)f2bf(f - bf2f(h));
      }
      *(bf16x8*)(ahs + Ab * 64 + Asl) = hi;
      *(bf16x8*)(als + Ab * 64 + Asl) = lo;
    }
    __syncthreads();  // LDS tile ready
    // ---- prefetch next step (overlaps MFMA phase) ----
    if (ks < 15) {
      const float* pB = rbB + (size_t)(ks + 1) * 64 * OO;
      const float* pA = rbA + (ks + 1) * 64;
      bv0 = *(const float4*)(pB + 0);
      bv1 = *(const float4*)(pB + 4);
      bv2 = *(const float4*)(pB + 8);
      bv3 = *(const float4*)(pB + 12);
      av0 = *(const float4*)(pA + 0);
      av1 = *(const float4*)(pA + 4);
    }
    // ---- fragments + MFMA ----
#pragma unroll
    for (int kc = 0; kc < 2; ++kc) {
      const int gq = kc * 4 + q;
      const int o = wave * 16 + l15;
      const int bsl = (gq ^ (o & 7)) << 3;
      bf16x8 bh = *(const bf16x8*)(rTh + o * 64 + bsl);
      bf16x8 bl = *(const bf16x8*)(rTl + o * 64 + bsl);
#pragma unroll
      for (int mt = 0; mt < 2; ++mt) {
        const int b = mt * 16 + l15;
        const int asl = (gq ^ (b & 7)) << 3;
        bf16x8 ah = *(const bf16x8*)(ahs + b * 64 + asl);
        bf16x8 al = *(const bf16x8*)(als + b * 64 + asl);
        acc[mt] = __builtin_amdgcn_mfma_f32_16x16x32_bf16(ah, bh, acc[mt], 0, 0, 0);
        acc[mt] = __builtin_amdgcn_mfma_f32_16x16x32_bf16(ah, bl, acc[mt], 0, 0, 0);
        acc[mt] = __builtin_amdgcn_mfma_f32_16x16x32_bf16(al, bh, acc[mt], 0, 0, 0);
      }
    }
  }

  // epilogue: b = mt*16 + q*4 + rr, o = ob + wave*16 + l15
#pragma unroll
  for (int mt = 0; mt < 2; ++mt)
#pragma unroll
    for (int rr = 0; rr < 4; ++rr) {
      const int b = mt * 16 + q * 4 + rr;
      outP[(size_t)(ksp * 32 + b) * OO + ob + wave * 16 + l15] = acc[mt][rr];
    }
}

// ---------------- K5: out = sum over 32 k-splits ----------------
__global__ __launch_bounds__(128) void nv_k5(const float* __restrict__ outP,
                                             float* __restrict__ out) {
  const int idx = blockIdx.x * 128 + threadIdx.x;  // 0..32767
  float s = 0.f;
#pragma unroll 8
  for (int sp = 0; sp < 32; ++sp) s += outP[(size_t)sp * 32768 + idx];
  out[idx] = s;
}

extern "C" void kernel_launch(void* const* d_in, const int* in_sizes, int n_in,
                              void* d_out, int out_size, void* d_ws, size_t ws_size,
                              hipStream_t stream) {
  const float* x = (const float*)d_in[0];
  const float* weight = (const float*)d_in[1];
  const float* bias = (const float*)d_in[2];
  const float* centers = (const float*)d_in[3];
  const float* reduc = (const float*)d_in[4];
  float* out = (float*)d_out;
  float* ws = (float*)d_ws;

  float* xaggP = ws;                          // [0, 8M)
  float* full = ws + 8388608;                 // [8M, 9M)
  float* outP = ws + 9437184;                 // [9M, 10M)
  ushort* whT = (ushort*)(ws + 10485760);     // 32768 ushorts
  float* sum_w = ws + 10502144;
  float* s1 = sum_w + 2048;
  float* scale = sum_w + 4096;

  nv_k0<<<136, 256, 0, stream>>>(weight, whT, sum_w);
  nv_k12<<<dim3(8, 32), 512, 0, stream>>>(x, whT, bias, xaggP, sum_w);
  nv_k3a<<<dim3(64, 32), 128, 0, stream>>>(xaggP, full, centers, sum_w, s1);
  nv_k3b<<<32, 64, 0, stream>>>(s1, scale);
  nv_k4<<<dim3(16, 32), 256, 0, stream>>>(full, scale, reduc, outP);
  nv_k5<<<256, 128, 0, stream>>>(outP, out);
}